// Round 20
// baseline (715.044 us; speedup 1.0000x reference)
//
#include <hip/hip_runtime.h>

// Round 20 — r19 + gemm<1> retuned for packing: BK=32 single-khalf
// double-buffer (64KB LDS -> 2 blocks/CU; all 384 blocks co-resident).
// Guide "minimum 2-phase" schedule: STAGE(nxt) -> ds_read cur -> 32 MFMA
// -> vmcnt(0)+barrier; co-resident block hides the drain (m114 overlap).
// gemm<0> keeps the r18 8-phase kernel (perfect 1-round packing already).
// Flash r19 (K via DMA), aux r16. Validated base: 630.5us.

typedef __attribute__((ext_vector_type(8))) short short8;
typedef __attribute__((ext_vector_type(4))) short short4v;
typedef __attribute__((ext_vector_type(4))) float f32x4;

#define LORA_SCALE 2.0f
#define INV_SQRT_HD 0.08838834764831845f

static __device__ __forceinline__ unsigned short f2bf(float f) {
  union { float f; unsigned int u; } v; v.f = f;
  unsigned int r = (v.u + 0x7fffu + ((v.u >> 16) & 1u)) >> 16;
  return (unsigned short)r;
}
static __device__ __forceinline__ float bf2f(unsigned short h) {
  union { unsigned int u; float f; } v; v.u = ((unsigned int)h) << 16;
  return v.f;
}

#define GL16(src, dst) __builtin_amdgcn_global_load_lds( \
    (const unsigned int __attribute__((address_space(1)))*)(src), \
    (unsigned int __attribute__((address_space(3)))*)(dst), 16, 0, 0)

#define VMC4() asm volatile("s_waitcnt vmcnt(4)" ::: "memory")
#define VMC0() asm volatile("s_waitcnt vmcnt(0)" ::: "memory")
#define BARX() __builtin_amdgcn_s_barrier()

// ---------------------------------------------------------------- GEMM 256x256, BK=64 8-phase (r18) — used for O-proj
template <int BF16OUT>
__global__ __launch_bounds__(512, 2) void gemm256_kernel(
    const unsigned short* __restrict__ A,
    const unsigned short* __restrict__ B,
    void* __restrict__ C, int K, int ldc, int T)
{
  __shared__ unsigned short As[2][2][8192];
  __shared__ unsigned short Bs[2][2][8192];
  const int tid = threadIdx.x;
  const int w = tid >> 6, l = tid & 63;
  const int l15 = l & 15, lhi = l >> 4;
  const int gx = gridDim.x;
  const int flat = blockIdx.y * gx + blockIdx.x;
  const int chunk = (gx * gridDim.y) >> 3;
  const int swz = (flat & 7) * chunk + (flat >> 3);
  const int m0 = (swz / gx) * 256, n0 = (swz % gx) * 256;
  const int wm = (w >> 2) * 128, wn = (w & 3) * 64;

  const f32x4 vz = {0.f, 0.f, 0.f, 0.f};
  f32x4 acc[8][4];
#pragma unroll
  for (int i = 0; i < 8; ++i)
#pragma unroll
    for (int j = 0; j < 4; ++j) acc[i][j] = vz;

  const int srow = tid >> 2, sg = tid & 3;
  const int sgsw = sg ^ ((tid >> 3) & 3);
  const unsigned short* gA = A + (size_t)(m0 + srow) * K + sgsw * 8;
  const unsigned short* gB = B + (size_t)(n0 + srow) * K + sgsw * 8;
  const size_t rK = (size_t)128 * K;
  const int ld0 = srow * 32 + sg * 8;

#define STAGE_A(buf, kh, kb) do { \
    GL16(gA + (kb) + (kh) * 32, &As[buf][kh][ld0]); \
    GL16(gA + rK + (kb) + (kh) * 32, &As[buf][kh][4096 + ld0]); } while (0)
#define STAGE_B(buf, kh, kb) do { \
    GL16(gB + (kb) + (kh) * 32, &Bs[buf][kh][ld0]); \
    GL16(gB + rK + (kb) + (kh) * 32, &Bs[buf][kh][4096 + ld0]); } while (0)
#define LDA8(buf, kc) do { \
    _Pragma("unroll") for (int mi = 0; mi < 8; ++mi) { \
      int r = wm + mi * 16 + l15; \
      af[mi] = *(const short8*)&As[buf][kc][r * 32 + ((lhi ^ ((r >> 1) & 3)) << 3)]; } } while (0)
#define LDB1(buf, kc, ni) \
    (*(const short8*)&Bs[buf][kc][(wn + (ni) * 16 + l15) * 32 + \
        ((lhi ^ (((wn + (ni) * 16 + l15) >> 1) & 3)) << 3)])
#define MM16(bx, by, cx, cy) do { \
    __builtin_amdgcn_s_setprio(1); \
    _Pragma("unroll") for (int mi = 0; mi < 8; ++mi) { \
      acc[mi][cx] = __builtin_amdgcn_mfma_f32_16x16x32_bf16(af[mi], bx, acc[mi][cx], 0, 0, 0); \
      acc[mi][cy] = __builtin_amdgcn_mfma_f32_16x16x32_bf16(af[mi], by, acc[mi][cy], 0, 0, 0); } \
    __builtin_amdgcn_s_setprio(0); } while (0)

  STAGE_A(0, 0, 0); STAGE_B(0, 0, 0); STAGE_A(0, 1, 0); STAGE_B(0, 1, 0);
  VMC4(); BARX();

  short8 af[8], b0, b1, b2, b3;
  for (int t = 0; t < T - 1; ++t) {
    const int cur = t & 1, nxt = cur ^ 1;
    const int kb = (t + 1) * 64;
    LDA8(cur, 0);
    b0 = LDB1(cur, 0, 0); b1 = LDB1(cur, 0, 1);
    STAGE_A(nxt, 0, kb);
    MM16(b0, b1, 0, 1);
    b2 = LDB1(cur, 0, 2); b3 = LDB1(cur, 0, 3);
    STAGE_B(nxt, 0, kb);
    VMC4(); BARX();
    MM16(b2, b3, 2, 3);
    LDA8(cur, 1);
    b0 = LDB1(cur, 1, 0); b1 = LDB1(cur, 1, 1);
    STAGE_A(nxt, 1, kb);
    MM16(b0, b1, 0, 1);
    b2 = LDB1(cur, 1, 2); b3 = LDB1(cur, 1, 3);
    STAGE_B(nxt, 1, kb);
    VMC4(); BARX();
    MM16(b2, b3, 2, 3);
  }
  {
    const int cur = (T - 1) & 1;
    LDA8(cur, 0);
    b0 = LDB1(cur, 0, 0); b1 = LDB1(cur, 0, 1);
    MM16(b0, b1, 0, 1);
    b2 = LDB1(cur, 0, 2); b3 = LDB1(cur, 0, 3);
    VMC0(); BARX();
    MM16(b2, b3, 2, 3);
    LDA8(cur, 1);
    b0 = LDB1(cur, 1, 0); b1 = LDB1(cur, 1, 1);
    MM16(b0, b1, 0, 1);
    b2 = LDB1(cur, 1, 2); b3 = LDB1(cur, 1, 3);
    MM16(b2, b3, 2, 3);
  }
#pragma unroll
  for (int mi = 0; mi < 8; ++mi)
#pragma unroll
    for (int ni = 0; ni < 4; ++ni)
#pragma unroll
      for (int j = 0; j < 4; ++j) {
        size_t row = (size_t)(m0 + wm + mi * 16 + lhi * 4 + j);
        size_t col = (size_t)(n0 + wn + ni * 16 + l15);
        if (BF16OUT) ((unsigned short*)C)[row * ldc + col] = f2bf(acc[mi][ni][j]);
        else         ((float*)C)[row * ldc + col] = acc[mi][ni][j];
      }
#undef STAGE_A
#undef STAGE_B
#undef LDA8
#undef LDB1
#undef MM16
}

// ---------------------------------------------------------------- GEMM 256x256, BK=32 2-phase, 64KB LDS, 2 blocks/CU — QKV proj
template <int BF16OUT>
__global__ __launch_bounds__(512, 2) void gemm256b_kernel(
    const unsigned short* __restrict__ A,
    const unsigned short* __restrict__ B,
    void* __restrict__ C, int K, int ldc, int T)   // T = K/32
{
  __shared__ unsigned short As[2][8192];   // [buf][256 rows x 32 cols]
  __shared__ unsigned short Bs[2][8192];
  const int tid = threadIdx.x;
  const int w = tid >> 6, l = tid & 63;
  const int l15 = l & 15, lhi = l >> 4;
  const int gx = gridDim.x;
  const int flat = blockIdx.y * gx + blockIdx.x;
  const int chunk = (gx * gridDim.y) >> 3;
  const int swz = (flat & 7) * chunk + (flat >> 3);
  const int m0 = (swz / gx) * 256, n0 = (swz % gx) * 256;
  const int wm = (w >> 2) * 128, wn = (w & 3) * 64;

  const f32x4 vz = {0.f, 0.f, 0.f, 0.f};
  f32x4 acc[8][4];
#pragma unroll
  for (int i = 0; i < 8; ++i)
#pragma unroll
    for (int j = 0; j < 4; ++j) acc[i][j] = vz;

  const int srow = tid >> 2, sg = tid & 3;
  const int sgsw = sg ^ ((tid >> 3) & 3);
  const unsigned short* gA = A + (size_t)(m0 + srow) * K + sgsw * 8;
  const unsigned short* gB = B + (size_t)(n0 + srow) * K + sgsw * 8;
  const size_t rK = (size_t)128 * K;
  const int ld0 = srow * 32 + sg * 8;

#define STAGE_AB(buf, kb) do { \
    GL16(gA + (kb), &As[buf][ld0]); \
    GL16(gA + rK + (kb), &As[buf][4096 + ld0]); \
    GL16(gB + (kb), &Bs[buf][ld0]); \
    GL16(gB + rK + (kb), &Bs[buf][4096 + ld0]); } while (0)
#define LDA8(buf) do { \
    _Pragma("unroll") for (int mi = 0; mi < 8; ++mi) { \
      int r = wm + mi * 16 + l15; \
      af[mi] = *(const short8*)&As[buf][r * 32 + ((lhi ^ ((r >> 1) & 3)) << 3)]; } } while (0)
#define LDB1(buf, ni) \
    (*(const short8*)&Bs[buf][(wn + (ni) * 16 + l15) * 32 + \
        ((lhi ^ (((wn + (ni) * 16 + l15) >> 1) & 3)) << 3)])
#define MM16(bx, by, cx, cy) do { \
    __builtin_amdgcn_s_setprio(1); \
    _Pragma("unroll") for (int mi = 0; mi < 8; ++mi) { \
      acc[mi][cx] = __builtin_amdgcn_mfma_f32_16x16x32_bf16(af[mi], bx, acc[mi][cx], 0, 0, 0); \
      acc[mi][cy] = __builtin_amdgcn_mfma_f32_16x16x32_bf16(af[mi], by, acc[mi][cy], 0, 0, 0); } \
    __builtin_amdgcn_s_setprio(0); } while (0)

  // prologue: stage tile 0, drain, publish
  STAGE_AB(0, 0);
  VMC0(); BARX();

  short8 af[8], b0, b1, b2, b3;
  for (int t = 0; t < T - 1; ++t) {
    const int cur = t & 1, nxt = cur ^ 1;
    // issue next-tile prefetch FIRST (hides under ds_read + 32 MFMA + other block)
    STAGE_AB(nxt, (t + 1) * 32);
    LDA8(cur);
    b0 = LDB1(cur, 0); b1 = LDB1(cur, 1);
    MM16(b0, b1, 0, 1);
    b2 = LDB1(cur, 2); b3 = LDB1(cur, 3);
    MM16(b2, b3, 2, 3);
    VMC0(); BARX();          // drain prefetch + publish nxt
  }
  { // last tile (no prefetch)
    const int cur = (T - 1) & 1;
    LDA8(cur);
    b0 = LDB1(cur, 0); b1 = LDB1(cur, 1);
    MM16(b0, b1, 0, 1);
    b2 = LDB1(cur, 2); b3 = LDB1(cur, 3);
    MM16(b2, b3, 2, 3);
  }
#pragma unroll
  for (int mi = 0; mi < 8; ++mi)
#pragma unroll
    for (int ni = 0; ni < 4; ++ni)
#pragma unroll
      for (int j = 0; j < 4; ++j) {
        size_t row = (size_t)(m0 + wm + mi * 16 + lhi * 4 + j);
        size_t col = (size_t)(n0 + wn + ni * 16 + l15);
        if (BF16OUT) ((unsigned short*)C)[row * ldc + col] = f2bf(acc[mi][ni][j]);
        else         ((float*)C)[row * ldc + col] = acc[mi][ni][j];
      }
#undef STAGE_AB
#undef LDA8
#undef LDB1
#undef MM16
}

// ---------------------------------------------------------------- flash per-tile body (r14 verbatim)
__device__ __forceinline__ void flash_tile(
    const unsigned short* __restrict__ Ks,
    const unsigned short* __restrict__ Vt,
    unsigned short* __restrict__ Psw,
    const short8 (&qf)[2][4], f32x4 (&po)[2][8],
    float (&mrun)[2][4], float (&lrun)[2][4],
    int kv0, int qw0, int l15, int lhi)
{
  const f32x4 vzero = {0.f, 0.f, 0.f, 0.f};
  f32x4 sa[2][4];
#pragma unroll
  for (int mf = 0; mf < 2; ++mf)
#pragma unroll
    for (int nf = 0; nf < 4; ++nf) sa[mf][nf] = vzero;
  __builtin_amdgcn_s_setprio(1);
#pragma unroll
  for (int kc = 0; kc < 4; ++kc) {
    short8 kf[4];
#pragma unroll
    for (int nf = 0; nf < 4; ++nf) {
      int row = nf * 16 + l15;
      kf[nf] = *(const short8*)&Ks[row * 128 + ((kc * 32 + lhi * 8) ^ ((row & 7) << 3))];
    }
#pragma unroll
    for (int mf = 0; mf < 2; ++mf)
#pragma unroll
      for (int nf = 0; nf < 4; ++nf)
        sa[mf][nf] = __builtin_amdgcn_mfma_f32_16x16x32_bf16(qf[mf][kc], kf[nf], sa[mf][nf], 0, 0, 0);
  }
  __builtin_amdgcn_s_setprio(0);
  const bool diag = (kv0 + 63) > qw0;
#pragma unroll
  for (int mf = 0; mf < 2; ++mf) {
#pragma unroll
    for (int nf = 0; nf < 4; ++nf)
#pragma unroll
      for (int j = 0; j < 4; ++j) {
        float v = sa[mf][nf][j] * INV_SQRT_HD;
        if (diag) {
          int kvc = kv0 + nf * 16 + l15;
          int qr  = qw0 + mf * 16 + lhi * 4 + j;
          if (kvc > qr) v = -1e30f;
        }
        sa[mf][nf][j] = v;
      }
#pragma unroll
    for (int j = 0; j < 4; ++j) {
      float rm = fmaxf(fmaxf(sa[mf][0][j], sa[mf][1][j]), fmaxf(sa[mf][2][j], sa[mf][3][j]));
#pragma unroll
      for (int d = 1; d < 16; d <<= 1) rm = fmaxf(rm, __shfl_xor(rm, d));
      float mnew = fmaxf(mrun[mf][j], rm);
      float sc = __expf(mrun[mf][j] - mnew);
      float rs = 0.f;
#pragma unroll
      for (int nf = 0; nf < 4; ++nf) {
        float p = __expf(sa[mf][nf][j] - mnew);
        sa[mf][nf][j] = p;
        rs += p;
      }
#pragma unroll
      for (int d = 1; d < 16; d <<= 1) rs += __shfl_xor(rs, d);
      lrun[mf][j] = lrun[mf][j] * sc + rs;
      mrun[mf][j] = mnew;
#pragma unroll
      for (int df = 0; df < 8; ++df) po[mf][df][j] *= sc;
    }
#pragma unroll
    for (int j = 0; j < 4; ++j) {
      int q = mf * 16 + lhi * 4 + j;
      int sq = (q & 7) << 3;
#pragma unroll
      for (int nf = 0; nf < 4; ++nf)
        Psw[q * 64 + ((nf * 16 + l15) ^ sq)] = f2bf(sa[mf][nf][j]);
    }
  }
  __builtin_amdgcn_s_setprio(1);
#pragma unroll
  for (int kc2 = 0; kc2 < 2; ++kc2) {
    short8 pf[2];
#pragma unroll
    for (int mf = 0; mf < 2; ++mf) {
      int q = mf * 16 + l15;
      pf[mf] = *(const short8*)&Psw[q * 64 + ((kc2 * 32 + lhi * 8) ^ ((q & 7) << 3))];
    }
#pragma unroll
    for (int df = 0; df < 8; ++df) {
      int d = df * 16 + l15;
      int sv = ((d & 7) ^ ((d >> 3) & 7)) << 3;
      short8 vf = *(const short8*)&Vt[d * 64 + ((kc2 * 32 + lhi * 8) ^ sv)];
#pragma unroll
      for (int mf = 0; mf < 2; ++mf)
        po[mf][df] = __builtin_amdgcn_mfma_f32_16x16x32_bf16(pf[mf], vf, po[mf][df], 0, 0, 0);
    }
  }
  __builtin_amdgcn_s_setprio(0);
}

// ---------------------------------------------------------------- flash attention (r19: pairing + K via DMA)
__global__ __launch_bounds__(512, 2) void flash_kernel(
    const unsigned short* __restrict__ qkv,
    unsigned short* __restrict__ outA)
{
  __shared__ unsigned short Ks[64 * 128];
  __shared__ unsigned short Vt[128 * 64];
  __shared__ unsigned short Ps[8][32 * 64];
  const int tid = threadIdx.x;
  const int w = tid >> 6, l = tid & 63;
  const int l15 = l & 15, lhi = l >> 4;
  const int h = blockIdx.y, b = blockIdx.z;
  const int p = (b == 0) ? (int)blockIdx.x : 7 - (int)blockIdx.x;
  const int qt = 2 * p + (w >> 2);
  const int qw0 = qt * 128 + (w & 3) * 32;
  const int kh = h >> 2;
  const size_t rowb = (size_t)b * 2048;

  short8 qf[2][4];
#pragma unroll
  for (int mf = 0; mf < 2; ++mf)
#pragma unroll
    for (int kc = 0; kc < 4; ++kc)
      qf[mf][kc] = *(const short8*)&qkv[(rowb + qw0 + mf * 16 + l15) * 6144 + h * 128 + kc * 32 + lhi * 8];

  const f32x4 vzero = {0.f, 0.f, 0.f, 0.f};
  f32x4 po[2][8];
  float mrun[2][4], lrun[2][4];
#pragma unroll
  for (int mf = 0; mf < 2; ++mf) {
#pragma unroll
    for (int df = 0; df < 8; ++df) po[mf][df] = vzero;
#pragma unroll
    for (int j = 0; j < 4; ++j) { mrun[mf][j] = -1e30f; lrun[mf][j] = 0.f; }
  }

  const int vrg = tid >> 4;
  const int vg  = tid & 15;

  const int nt = 2 * (2 * p + 1) + 2;
  for (int t = 0; t < nt; ++t) {
    const int kv0 = t * 64;
#pragma unroll
    for (int it = 0; it < 2; ++it) {
      int idx = it * 512 + tid;
      int r = idx >> 4, g = idx & 15;
      GL16(&qkv[(rowb + kv0 + r) * 6144 + 4096 + kh * 128 + ((g * 8) ^ ((r & 7) << 3))],
           &Ks[r * 128 + g * 8]);
    }
    if (tid < 256) {
      short8 v0, v1, v2, v3;
      const size_t vb = (rowb + kv0 + vrg * 4) * 6144 + kh * 128 + vg * 8 + 5120;
      v0 = *(const short8*)&qkv[vb];
      v1 = *(const short8*)&qkv[vb + 6144];
      v2 = *(const short8*)&qkv[vb + 12288];
      v3 = *(const short8*)&qkv[vb + 18432];
#pragma unroll
      for (int e = 0; e < 8; ++e) {
        int d = vg * 8 + e;
        int sv = ((d & 7) ^ ((d >> 3) & 7)) << 3;
        short4v o; o[0] = v0[e]; o[1] = v1[e]; o[2] = v2[e]; o[3] = v3[e];
        *(short4v*)&Vt[d * 64 + ((vrg * 4) ^ sv)] = o;
      }
    }
    __syncthreads();
    if (kv0 <= qw0 + 31)
      flash_tile(Ks, Vt, Ps[w], qf, po, mrun, lrun, kv0, qw0, l15, lhi);
    __syncthreads();
  }
#pragma unroll
  for (int mf = 0; mf < 2; ++mf)
#pragma unroll
    for (int df = 0; df < 8; ++df)
#pragma unroll
      for (int j = 0; j < 4; ++j) {
        size_t q = (size_t)(qw0 + mf * 16 + lhi * 4 + j);
        int d = df * 16 + l15;
        outA[(rowb + q) * 4160 + h * 128 + d] = f2bf(po[mf][df][j] / lrun[mf][j]);
      }
}

// ---------------------------------------------------------------- aux kernels (r16 consolidated)
__global__ __launch_bounds__(256) void fold_all_kernel(
    const float* __restrict__ wq, const float* __restrict__ wk, const float* __restrict__ wv,
    const float* __restrict__ bq, const float* __restrict__ bk, const float* __restrict__ bv,
    const float* __restrict__ aq, const float* __restrict__ ak, const float* __restrict__ av,
    unsigned short* __restrict__ W)
{
  __shared__ unsigned short als[16][512];
  const int tid = threadIdx.x;
  const int ng0 = blockIdx.x * 8;
  const int c0 = blockIdx.y * 512;
  const float *wsrc, *bsrc, *asrc;
  int nl0;
  if (ng0 < 4096)      { wsrc = wq; bsrc = bq; asrc = aq; nl0 = ng0; }
  else if (ng0 < 5120) { wsrc = wk; bsrc = bk; asrc = ak; nl0 = ng0 - 4096; }
  else                 { wsrc = wv; bsrc = bv; asrc = av; nl0 = ng0 - 5120; }
#pragma unroll
  for (int it = 0; it < 8; ++it) {
    int flat = it * 1024 + tid * 4;
    int r = flat >> 9, c = flat & 511;
    f32x4 v = *(const f32x4*)&asrc[(size_t)r * 4096 + c0 + c];
    short4v o;
#pragma unroll
    for (int e = 0; e < 4; ++e) o[e] = (short)f2bf(LORA_SCALE * v[e]);
    *(short4v*)&als[r][c] = o;
  }
  __syncthreads();
  const int nr = tid >> 5;
  const int cb = (tid & 31) * 16;
  const float* wrow = wsrc + (size_t)(nl0 + nr) * 4096 + c0 + cb;
  const float* brow = bsrc + (size_t)(nl0 + nr) * 16;
  float bb[16];
#pragma unroll
  for (int r4 = 0; r4 < 4; ++r4) {
    f32x4 t = *(const f32x4*)&brow[r4 * 4];
#pragma unroll
    for (int e = 0; e < 4; ++e) bb[r4 * 4 + e] = t[e];
  }
  float acc[16];
#pragma unroll
  for (int j4 = 0; j4 < 4; ++j4) {
    f32x4 t = *(const f32x4*)&wrow[j4 * 4];
#pragma unroll
    for (int e = 0; e < 4; ++e) acc[j4 * 4 + e] = t[e];
  }
#pragma unroll
  for (int r = 0; r < 16; ++r) {
    short8 a0 = *(const short8*)&als[r][cb];
    short8 a1 = *(const short8*)&als[r][cb + 8];
    float br = bb[r];
#pragma unroll
    for (int e = 0; e < 8; ++e) {
      acc[e]     += br * bf2f((unsigned short)a0[e]);
      acc[8 + e] += br * bf2f((unsigned short)a1[e]);
    }
  }
  short8 o0, o1;
#pragma unroll
  for (int e = 0; e < 8; ++e) { o0[e] = (short)f2bf(acc[e]); o1[e] = (short)f2bf(acc[8 + e]); }
  unsigned short* dst = W + (size_t)(ng0 + nr) * 4096 + c0 + cb;
  *(short8*)&dst[0] = o0;
  *(short8*)&dst[8] = o1;
}

__global__ void build_wo_kernel(const float* __restrict__ wo, const float* __restrict__ bo,
                                unsigned short* __restrict__ W)
{
  int idx = blockIdx.x * 256 + threadIdx.x;
  int n = idx / 520;
  int c8 = (idx - n * 520) * 8;
  short8 o;
  if (c8 < 4096) {
    const float* src = wo + (size_t)n * 4096 + c8;
    f32x4 a = *(const f32x4*)&src[0];
    f32x4 b2 = *(const f32x4*)&src[4];
#pragma unroll
    for (int e = 0; e < 4; ++e) { o[e] = (short)f2bf(a[e]); o[4 + e] = (short)f2bf(b2[e]); }
  } else {
#pragma unroll
    for (int e = 0; e < 8; ++e) {
      int j = c8 + e - 4096;
      float v = (j < 16) ? bo[(size_t)n * 16 + j] : 0.f;
      o[e] = (short)f2bf(v);
    }
  }
  *(short8*)&W[(size_t)n * 4160 + c8] = o;
}

__global__ __launch_bounds__(256) void convert_t_kernel(
    const float* __restrict__ x, const float* __restrict__ ao,
    unsigned short* __restrict__ Xb, unsigned short* __restrict__ Ao)
{
  __shared__ float red[4][16];
  const int m = blockIdx.x;
  const int tid = threadIdx.x;
  const int w = tid >> 6, l = tid & 63;
  float part[16];
#pragma unroll
  for (int r = 0; r < 16; ++r) part[r] = 0.f;
#pragma unroll
  for (int it = 0; it < 4; ++it) {
    int k = it * 1024 + tid * 4;
    f32x4 xv = *(const f32x4*)&x[(size_t)m * 4096 + k];
    short4v o;
#pragma unroll
    for (int e = 0; e < 4; ++e) o[e] = (short)f2bf(xv[e]);
    *(short4v*)&Xb[(size_t)m * 4096 + k] = o;
#pragma unroll
    for (int r = 0; r < 16; ++r) {
      f32x4 av = *(const f32x4*)&ao[(size_t)r * 4096 + k];
      part[r] += xv[0] * av[0] + xv[1] * av[1] + xv[2] * av[2] + xv[3] * av[3];
    }
  }
#pragma unroll
  for (int d = 1; d < 64; d <<= 1)
#pragma unroll
    for (int r = 0; r < 16; ++r) part[r] += __shfl_xor(part[r], d);
  if (l == 0)
#pragma unroll
    for (int r = 0; r < 16; ++r) red[w][r] = part[r];
  __syncthreads();
  if (tid < 64) {
    float v = 0.f;
    if (tid < 16) v = LORA_SCALE * (red[0][tid] + red[1][tid] + red[2][tid] + red[3][tid]);
    Ao[(size_t)m * 4160 + 4096 + tid] = f2bf(v);
  }
}

__global__ void rope_kernel(unsigned short* __restrict__ qkv,
                            const float* __restrict__ fcos,
                            const float* __restrict__ fsin)
{
  int idx = blockIdx.x * 256 + threadIdx.x;
  int m = idx / 640;
  int c8 = (idx - m * 640) * 8;
  int s = m & 2047;
  int i0 = (c8 & 127) >> 1;
  unsigned short* p = qkv + (size_t)m * 6144 + c8;
  short8 v = *(short8*)p;
  f32x4 c = *(const f32x4*)&fcos[s * 64 + i0];
  f32x4 sn = *(const f32x4*)&fsin[s * 64 + i0];
  short8 o;
#pragma unroll
  for (int pr = 0; pr < 4; ++pr) {
    float re = bf2f((unsigned short)v[2 * pr]);
    float im = bf2f((unsigned short)v[2 * pr + 1]);
    o[2 * pr]     = (short)f2bf(re * c[pr] - im * sn[pr]);
    o[2 * pr + 1] = (short)f2bf(re * sn[pr] + im * c[pr]);
  }
  *(short8*)p = o;
}

// ---------------------------------------------------------------- launch
extern "C" void kernel_launch(void* const* d_in, const int* in_sizes, int n_in,
                              void* d_out, int out_size, void* d_ws, size_t ws_size,
                              hipStream_t stream) {
  (void)in_sizes; (void)n_in; (void)out_size; (void)ws_size;
  const float* x    = (const float*)d_in[0];
  const float* w_q  = (const float*)d_in[1];
  const float* w_k  = (const float*)d_in[2];
  const float* w_v  = (const float*)d_in[3];
  const float* w_o  = (const float*)d_in[4];
  const float* la_q = (const float*)d_in[5];
  const float* lb_q = (const float*)d_in[6];
  const float* la_k = (const float*)d_in[7];
  const float* lb_k = (const float*)d_in[8];
  const float* la_v = (const float*)d_in[9];
  const float* lb_v = (const float*)d_in[10];
  const float* la_o = (const float*)d_in[11];
  const float* lb_o = (const float*)d_in[12];
  const float* fcos = (const float*)d_in[15];
  const float* fsin = (const float*)d_in[16];

  unsigned short* Wqkv = (unsigned short*)d_ws;              // 6144*4096
  unsigned short* Wo   = Wqkv + (size_t)6144 * 4096;         // 4096*4160
  unsigned short* Xbf  = Wo + (size_t)4096 * 4160;           // 4096*4096
  unsigned short* QKV  = Xbf + (size_t)4096 * 4096;          // 4096*6144
  unsigned short* Ao   = QKV + (size_t)4096 * 6144;          // 4096*4160

  dim3 blk(256);
  fold_all_kernel<<<dim3(768, 8), blk, 0, stream>>>(
      w_q, w_k, w_v, lb_q, lb_k, lb_v, la_q, la_k, la_v, Wqkv);
  build_wo_kernel<<<8320, blk, 0, stream>>>(w_o, lb_o, Wo);
  convert_t_kernel<<<4096, blk, 0, stream>>>(x, la_o, Xbf, Ao);
  gemm256b_kernel<1><<<dim3(24, 16), dim3(512), 0, stream>>>(Xbf, Wqkv, QKV, 4096, 6144, 128);
  rope_kernel<<<10240, blk, 0, stream>>>(QKV, fcos, fsin);
  flash_kernel<<<dim3(8, 32, 2), dim3(512), 0, stream>>>(QKV, Ao);
  gemm256_kernel<0><<<dim3(16, 16), dim3(512), 0, stream>>>(Ao, Wo, d_out, 4160, 4096, 65);
}

// Round 21
// 679.561 us; speedup vs baseline: 1.0522x; 1.0522x over previous
//
#include <hip/hip_runtime.h>

// Round 21 — r19 base + gemm<1> as BK=32 COUNTED-vmcnt double-buffer:
// 64KB LDS -> 2 blocks/CU (all 384 blocks co-resident, pack=1.0) while
// keeping the never-drain property (vmcnt(4), 4 loads always in flight)
// that r20's 2-phase lacked (its vmcnt(0) drain = 624 TF ceiling, m233).
// Per tile: ds_read 12 frags -> lgkmcnt(0)+barrier (read-before-refill
// fence) -> STAGE(cur <- t+2) -> 32 MFMA -> vmcnt(4) -> barrier.
// gemm<0> keeps r18 8-phase (perfect packing already). Flash/aux = r19.

typedef __attribute__((ext_vector_type(8))) short short8;
typedef __attribute__((ext_vector_type(4))) short short4v;
typedef __attribute__((ext_vector_type(4))) float f32x4;

#define LORA_SCALE 2.0f
#define INV_SQRT_HD 0.08838834764831845f

static __device__ __forceinline__ unsigned short f2bf(float f) {
  union { float f; unsigned int u; } v; v.f = f;
  unsigned int r = (v.u + 0x7fffu + ((v.u >> 16) & 1u)) >> 16;
  return (unsigned short)r;
}
static __device__ __forceinline__ float bf2f(unsigned short h) {
  union { unsigned int u; float f; } v; v.u = ((unsigned int)h) << 16;
  return v.f;
}

#define GL16(src, dst) __builtin_amdgcn_global_load_lds( \
    (const unsigned int __attribute__((address_space(1)))*)(src), \
    (unsigned int __attribute__((address_space(3)))*)(dst), 16, 0, 0)

#define VMC4() asm volatile("s_waitcnt vmcnt(4)" ::: "memory")
#define VMC0() asm volatile("s_waitcnt vmcnt(0)" ::: "memory")
#define LGK0() asm volatile("s_waitcnt lgkmcnt(0)" ::: "memory")
#define BARX() __builtin_amdgcn_s_barrier()

// ---------------------------------------------------------------- GEMM 256x256, BK=64 8-phase (r18) — O-proj
template <int BF16OUT>
__global__ __launch_bounds__(512, 2) void gemm256_kernel(
    const unsigned short* __restrict__ A,
    const unsigned short* __restrict__ B,
    void* __restrict__ C, int K, int ldc, int T)
{
  __shared__ unsigned short As[2][2][8192];
  __shared__ unsigned short Bs[2][2][8192];
  const int tid = threadIdx.x;
  const int w = tid >> 6, l = tid & 63;
  const int l15 = l & 15, lhi = l >> 4;
  const int gx = gridDim.x;
  const int flat = blockIdx.y * gx + blockIdx.x;
  const int chunk = (gx * gridDim.y) >> 3;
  const int swz = (flat & 7) * chunk + (flat >> 3);
  const int m0 = (swz / gx) * 256, n0 = (swz % gx) * 256;
  const int wm = (w >> 2) * 128, wn = (w & 3) * 64;

  const f32x4 vz = {0.f, 0.f, 0.f, 0.f};
  f32x4 acc[8][4];
#pragma unroll
  for (int i = 0; i < 8; ++i)
#pragma unroll
    for (int j = 0; j < 4; ++j) acc[i][j] = vz;

  const int srow = tid >> 2, sg = tid & 3;
  const int sgsw = sg ^ ((tid >> 3) & 3);
  const unsigned short* gA = A + (size_t)(m0 + srow) * K + sgsw * 8;
  const unsigned short* gB = B + (size_t)(n0 + srow) * K + sgsw * 8;
  const size_t rK = (size_t)128 * K;
  const int ld0 = srow * 32 + sg * 8;

#define STAGE_A(buf, kh, kb) do { \
    GL16(gA + (kb) + (kh) * 32, &As[buf][kh][ld0]); \
    GL16(gA + rK + (kb) + (kh) * 32, &As[buf][kh][4096 + ld0]); } while (0)
#define STAGE_B(buf, kh, kb) do { \
    GL16(gB + (kb) + (kh) * 32, &Bs[buf][kh][ld0]); \
    GL16(gB + rK + (kb) + (kh) * 32, &Bs[buf][kh][4096 + ld0]); } while (0)
#define LDA8(buf, kc) do { \
    _Pragma("unroll") for (int mi = 0; mi < 8; ++mi) { \
      int r = wm + mi * 16 + l15; \
      af[mi] = *(const short8*)&As[buf][kc][r * 32 + ((lhi ^ ((r >> 1) & 3)) << 3)]; } } while (0)
#define LDB1(buf, kc, ni) \
    (*(const short8*)&Bs[buf][kc][(wn + (ni) * 16 + l15) * 32 + \
        ((lhi ^ (((wn + (ni) * 16 + l15) >> 1) & 3)) << 3)])
#define MM16(bx, by, cx, cy) do { \
    __builtin_amdgcn_s_setprio(1); \
    _Pragma("unroll") for (int mi = 0; mi < 8; ++mi) { \
      acc[mi][cx] = __builtin_amdgcn_mfma_f32_16x16x32_bf16(af[mi], bx, acc[mi][cx], 0, 0, 0); \
      acc[mi][cy] = __builtin_amdgcn_mfma_f32_16x16x32_bf16(af[mi], by, acc[mi][cy], 0, 0, 0); } \
    __builtin_amdgcn_s_setprio(0); } while (0)

  STAGE_A(0, 0, 0); STAGE_B(0, 0, 0); STAGE_A(0, 1, 0); STAGE_B(0, 1, 0);
  VMC4(); BARX();

  short8 af[8], b0, b1, b2, b3;
  for (int t = 0; t < T - 1; ++t) {
    const int cur = t & 1, nxt = cur ^ 1;
    const int kb = (t + 1) * 64;
    LDA8(cur, 0);
    b0 = LDB1(cur, 0, 0); b1 = LDB1(cur, 0, 1);
    STAGE_A(nxt, 0, kb);
    MM16(b0, b1, 0, 1);
    b2 = LDB1(cur, 0, 2); b3 = LDB1(cur, 0, 3);
    STAGE_B(nxt, 0, kb);
    VMC4(); BARX();
    MM16(b2, b3, 2, 3);
    LDA8(cur, 1);
    b0 = LDB1(cur, 1, 0); b1 = LDB1(cur, 1, 1);
    STAGE_A(nxt, 1, kb);
    MM16(b0, b1, 0, 1);
    b2 = LDB1(cur, 1, 2); b3 = LDB1(cur, 1, 3);
    STAGE_B(nxt, 1, kb);
    VMC4(); BARX();
    MM16(b2, b3, 2, 3);
  }
  {
    const int cur = (T - 1) & 1;
    LDA8(cur, 0);
    b0 = LDB1(cur, 0, 0); b1 = LDB1(cur, 0, 1);
    MM16(b0, b1, 0, 1);
    b2 = LDB1(cur, 0, 2); b3 = LDB1(cur, 0, 3);
    VMC0(); BARX();
    MM16(b2, b3, 2, 3);
    LDA8(cur, 1);
    b0 = LDB1(cur, 1, 0); b1 = LDB1(cur, 1, 1);
    MM16(b0, b1, 0, 1);
    b2 = LDB1(cur, 1, 2); b3 = LDB1(cur, 1, 3);
    MM16(b2, b3, 2, 3);
  }
#pragma unroll
  for (int mi = 0; mi < 8; ++mi)
#pragma unroll
    for (int ni = 0; ni < 4; ++ni)
#pragma unroll
      for (int j = 0; j < 4; ++j) {
        size_t row = (size_t)(m0 + wm + mi * 16 + lhi * 4 + j);
        size_t col = (size_t)(n0 + wn + ni * 16 + l15);
        if (BF16OUT) ((unsigned short*)C)[row * ldc + col] = f2bf(acc[mi][ni][j]);
        else         ((float*)C)[row * ldc + col] = acc[mi][ni][j];
      }
#undef STAGE_A
#undef STAGE_B
#undef LDA8
#undef LDB1
#undef MM16
}

// ---------------------------------------------------------------- GEMM 256x256, BK=32 counted-vmcnt, 64KB LDS — QKV proj
template <int BF16OUT>
__global__ __launch_bounds__(512, 2) void gemm256c_kernel(
    const unsigned short* __restrict__ A,
    const unsigned short* __restrict__ B,
    void* __restrict__ C, int K, int ldc, int T)   // T = K/32 (>= 4)
{
  __shared__ unsigned short As[2][8192];   // [buf][256 rows x 32 cols]
  __shared__ unsigned short Bs[2][8192];
  const int tid = threadIdx.x;
  const int w = tid >> 6, l = tid & 63;
  const int l15 = l & 15, lhi = l >> 4;
  const int gx = gridDim.x;
  const int flat = blockIdx.y * gx + blockIdx.x;
  const int chunk = (gx * gridDim.y) >> 3;
  const int swz = (flat & 7) * chunk + (flat >> 3);
  const int m0 = (swz / gx) * 256, n0 = (swz % gx) * 256;
  const int wm = (w >> 2) * 128, wn = (w & 3) * 64;

  const f32x4 vz = {0.f, 0.f, 0.f, 0.f};
  f32x4 acc[8][4];
#pragma unroll
  for (int i = 0; i < 8; ++i)
#pragma unroll
    for (int j = 0; j < 4; ++j) acc[i][j] = vz;

  const int srow = tid >> 2, sg = tid & 3;
  const int sgsw = sg ^ ((tid >> 3) & 3);
  const unsigned short* gA = A + (size_t)(m0 + srow) * K + sgsw * 8;
  const unsigned short* gB = B + (size_t)(n0 + srow) * K + sgsw * 8;
  const size_t rK = (size_t)128 * K;
  const int ld0 = srow * 32 + sg * 8;

#define STAGE_AB(buf, kb) do { \
    GL16(gA + (kb), &As[buf][ld0]); \
    GL16(gA + rK + (kb), &As[buf][4096 + ld0]); \
    GL16(gB + (kb), &Bs[buf][ld0]); \
    GL16(gB + rK + (kb), &Bs[buf][4096 + ld0]); } while (0)
#define LDA8(buf) do { \
    _Pragma("unroll") for (int mi = 0; mi < 8; ++mi) { \
      int r = wm + mi * 16 + l15; \
      af[mi] = *(const short8*)&As[buf][r * 32 + ((lhi ^ ((r >> 1) & 3)) << 3)]; } } while (0)
#define LDB1(buf, ni) \
    (*(const short8*)&Bs[buf][(wn + (ni) * 16 + l15) * 32 + \
        ((lhi ^ (((wn + (ni) * 16 + l15) >> 1) & 3)) << 3)])
#define MM16(bx, by, cx, cy) do { \
    __builtin_amdgcn_s_setprio(1); \
    _Pragma("unroll") for (int mi = 0; mi < 8; ++mi) { \
      acc[mi][cx] = __builtin_amdgcn_mfma_f32_16x16x32_bf16(af[mi], bx, acc[mi][cx], 0, 0, 0); \
      acc[mi][cy] = __builtin_amdgcn_mfma_f32_16x16x32_bf16(af[mi], by, acc[mi][cy], 0, 0, 0); } \
    __builtin_amdgcn_s_setprio(0); } while (0)

  // prologue: stage tiles 0 and 1; retire tile 0 (4 newest stay in flight)
  STAGE_AB(0, 0);
  STAGE_AB(1, 32);
  VMC4(); BARX();
  // loop invariant at entry of tile t: buf[t&1] published; 4 loads
  // (tile t+1) outstanding.

  short8 af[8], b0, b1, b2, b3;
  for (int t = 0; t < T - 2; ++t) {
    const int cur = t & 1;
    // read ALL of buf[cur] into regs first
    LDA8(cur);
    b0 = LDB1(cur, 0); b1 = LDB1(cur, 1);
    b2 = LDB1(cur, 2); b3 = LDB1(cur, 3);
    LGK0(); BARX();                  // every wave done reading buf[cur]
    STAGE_AB(cur, (t + 2) * 32);     // refill cur with tile t+2 (DMA)
    MM16(b0, b1, 0, 1);
    MM16(b2, b3, 2, 3);
    VMC4(); BARX();                  // retire tile t+1's 4 loads; publish
  }
  { // tile T-2: no refill; drain tile T-1's loads at the end
    const int cur = (T - 2) & 1;
    LDA8(cur);
    b0 = LDB1(cur, 0); b1 = LDB1(cur, 1);
    b2 = LDB1(cur, 2); b3 = LDB1(cur, 3);
    MM16(b0, b1, 0, 1);
    MM16(b2, b3, 2, 3);
    VMC0(); BARX();                  // publish tile T-1
  }
  { // tile T-1
    const int cur = (T - 1) & 1;
    LDA8(cur);
    b0 = LDB1(cur, 0); b1 = LDB1(cur, 1);
    b2 = LDB1(cur, 2); b3 = LDB1(cur, 3);
    MM16(b0, b1, 0, 1);
    MM16(b2, b3, 2, 3);
  }
#pragma unroll
  for (int mi = 0; mi < 8; ++mi)
#pragma unroll
    for (int ni = 0; ni < 4; ++ni)
#pragma unroll
      for (int j = 0; j < 4; ++j) {
        size_t row = (size_t)(m0 + wm + mi * 16 + lhi * 4 + j);
        size_t col = (size_t)(n0 + wn + ni * 16 + l15);
        if (BF16OUT) ((unsigned short*)C)[row * ldc + col] = f2bf(acc[mi][ni][j]);
        else         ((float*)C)[row * ldc + col] = acc[mi][ni][j];
      }
#undef STAGE_AB
#undef LDA8
#undef LDB1
#undef MM16
}

// ---------------------------------------------------------------- flash per-tile body (r14 verbatim)
__device__ __forceinline__ void flash_tile(
    const unsigned short* __restrict__ Ks,
    const unsigned short* __restrict__ Vt,
    unsigned short* __restrict__ Psw,
    const short8 (&qf)[2][4], f32x4 (&po)[2][8],
    float (&mrun)[2][4], float (&lrun)[2][4],
    int kv0, int qw0, int l15, int lhi)
{
  const f32x4 vzero = {0.f, 0.f, 0.f, 0.f};
  f32x4 sa[2][4];
#pragma unroll
  for (int mf = 0; mf < 2; ++mf)
#pragma unroll
    for (int nf = 0; nf < 4; ++nf) sa[mf][nf] = vzero;
  __builtin_amdgcn_s_setprio(1);
#pragma unroll
  for (int kc = 0; kc < 4; ++kc) {
    short8 kf[4];
#pragma unroll
    for (int nf = 0; nf < 4; ++nf) {
      int row = nf * 16 + l15;
      kf[nf] = *(const short8*)&Ks[row * 128 + ((kc * 32 + lhi * 8) ^ ((row & 7) << 3))];
    }
#pragma unroll
    for (int mf = 0; mf < 2; ++mf)
#pragma unroll
      for (int nf = 0; nf < 4; ++nf)
        sa[mf][nf] = __builtin_amdgcn_mfma_f32_16x16x32_bf16(qf[mf][kc], kf[nf], sa[mf][nf], 0, 0, 0);
  }
  __builtin_amdgcn_s_setprio(0);
  const bool diag = (kv0 + 63) > qw0;
#pragma unroll
  for (int mf = 0; mf < 2; ++mf) {
#pragma unroll
    for (int nf = 0; nf < 4; ++nf)
#pragma unroll
      for (int j = 0; j < 4; ++j) {
        float v = sa[mf][nf][j] * INV_SQRT_HD;
        if (diag) {
          int kvc = kv0 + nf * 16 + l15;
          int qr  = qw0 + mf * 16 + lhi * 4 + j;
          if (kvc > qr) v = -1e30f;
        }
        sa[mf][nf][j] = v;
      }
#pragma unroll
    for (int j = 0; j < 4; ++j) {
      float rm = fmaxf(fmaxf(sa[mf][0][j], sa[mf][1][j]), fmaxf(sa[mf][2][j], sa[mf][3][j]));
#pragma unroll
      for (int d = 1; d < 16; d <<= 1) rm = fmaxf(rm, __shfl_xor(rm, d));
      float mnew = fmaxf(mrun[mf][j], rm);
      float sc = __expf(mrun[mf][j] - mnew);
      float rs = 0.f;
#pragma unroll
      for (int nf = 0; nf < 4; ++nf) {
        float p = __expf(sa[mf][nf][j] - mnew);
        sa[mf][nf][j] = p;
        rs += p;
      }
#pragma unroll
      for (int d = 1; d < 16; d <<= 1) rs += __shfl_xor(rs, d);
      lrun[mf][j] = lrun[mf][j] * sc + rs;
      mrun[mf][j] = mnew;
#pragma unroll
      for (int df = 0; df < 8; ++df) po[mf][df][j] *= sc;
    }
#pragma unroll
    for (int j = 0; j < 4; ++j) {
      int q = mf * 16 + lhi * 4 + j;
      int sq = (q & 7) << 3;
#pragma unroll
      for (int nf = 0; nf < 4; ++nf)
        Psw[q * 64 + ((nf * 16 + l15) ^ sq)] = f2bf(sa[mf][nf][j]);
    }
  }
  __builtin_amdgcn_s_setprio(1);
#pragma unroll
  for (int kc2 = 0; kc2 < 2; ++kc2) {
    short8 pf[2];
#pragma unroll
    for (int mf = 0; mf < 2; ++mf) {
      int q = mf * 16 + l15;
      pf[mf] = *(const short8*)&Psw[q * 64 + ((kc2 * 32 + lhi * 8) ^ ((q & 7) << 3))];
    }
#pragma unroll
    for (int df = 0; df < 8; ++df) {
      int d = df * 16 + l15;
      int sv = ((d & 7) ^ ((d >> 3) & 7)) << 3;
      short8 vf = *(const short8*)&Vt[d * 64 + ((kc2 * 32 + lhi * 8) ^ sv)];
#pragma unroll
      for (int mf = 0; mf < 2; ++mf)
        po[mf][df] = __builtin_amdgcn_mfma_f32_16x16x32_bf16(pf[mf], vf, po[mf][df], 0, 0, 0);
    }
  }
  __builtin_amdgcn_s_setprio(0);
}

// ---------------------------------------------------------------- flash attention (r19: pairing + K via DMA)
__global__ __launch_bounds__(512, 2) void flash_kernel(
    const unsigned short* __restrict__ qkv,
    unsigned short* __restrict__ outA)
{
  __shared__ unsigned short Ks[64 * 128];
  __shared__ unsigned short Vt[128 * 64];
  __shared__ unsigned short Ps[8][32 * 64];
  const int tid = threadIdx.x;
  const int w = tid >> 6, l = tid & 63;
  const int l15 = l & 15, lhi = l >> 4;
  const int h = blockIdx.y, b = blockIdx.z;
  const int p = (b == 0) ? (int)blockIdx.x : 7 - (int)blockIdx.x;
  const int qt = 2 * p + (w >> 2);
  const int qw0 = qt * 128 + (w & 3) * 32;
  const int kh = h >> 2;
  const size_t rowb = (size_t)b * 2048;

  short8 qf[2][4];
#pragma unroll
  for (int mf = 0; mf < 2; ++mf)
#pragma unroll
    for (int kc = 0; kc < 4; ++kc)
      qf[mf][kc] = *(const short8*)&qkv[(rowb + qw0 + mf * 16 + l15) * 6144 + h * 128 + kc * 32 + lhi * 8];

  const f32x4 vzero = {0.f, 0.f, 0.f, 0.f};
  f32x4 po[2][8];
  float mrun[2][4], lrun[2][4];
#pragma unroll
  for (int mf = 0; mf < 2; ++mf) {
#pragma unroll
    for (int df = 0; df < 8; ++df) po[mf][df] = vzero;
#pragma unroll
    for (int j = 0; j < 4; ++j) { mrun[mf][j] = -1e30f; lrun[mf][j] = 0.f; }
  }

  const int vrg = tid >> 4;
  const int vg  = tid & 15;

  const int nt = 2 * (2 * p + 1) + 2;
  for (int t = 0; t < nt; ++t) {
    const int kv0 = t * 64;
#pragma unroll
    for (int it = 0; it < 2; ++it) {
      int idx = it * 512 + tid;
      int r = idx >> 4, g = idx & 15;
      GL16(&qkv[(rowb + kv0 + r) * 6144 + 4096 + kh * 128 + ((g * 8) ^ ((r & 7) << 3))],
           &Ks[r * 128 + g * 8]);
    }
    if (tid < 256) {
      short8 v0, v1, v2, v3;
      const size_t vb = (rowb + kv0 + vrg * 4) * 6144 + kh * 128 + vg * 8 + 5120;
      v0 = *(const short8*)&qkv[vb];
      v1 = *(const short8*)&qkv[vb + 6144];
      v2 = *(const short8*)&qkv[vb + 12288];
      v3 = *(const short8*)&qkv[vb + 18432];
#pragma unroll
      for (int e = 0; e < 8; ++e) {
        int d = vg * 8 + e;
        int sv = ((d & 7) ^ ((d >> 3) & 7)) << 3;
        short4v o; o[0] = v0[e]; o[1] = v1[e]; o[2] = v2[e]; o[3] = v3[e];
        *(short4v*)&Vt[d * 64 + ((vrg * 4) ^ sv)] = o;
      }
    }
    __syncthreads();
    if (kv0 <= qw0 + 31)
      flash_tile(Ks, Vt, Ps[w], qf, po, mrun, lrun, kv0, qw0, l15, lhi);
    __syncthreads();
  }
#pragma unroll
  for (int mf = 0; mf < 2; ++mf)
#pragma unroll
    for (int df = 0; df < 8; ++df)
#pragma unroll
      for (int j = 0; j < 4; ++j) {
        size_t q = (size_t)(qw0 + mf * 16 + lhi * 4 + j);
        int d = df * 16 + l15;
        outA[(rowb + q) * 4160 + h * 128 + d] = f2bf(po[mf][df][j] / lrun[mf][j]);
      }
}

// ---------------------------------------------------------------- aux kernels (r16 consolidated)
__global__ __launch_bounds__(256) void fold_all_kernel(
    const float* __restrict__ wq, const float* __restrict__ wk, const float* __restrict__ wv,
    const float* __restrict__ bq, const float* __restrict__ bk, const float* __restrict__ bv,
    const float* __restrict__ aq, const float* __restrict__ ak, const float* __restrict__ av,
    unsigned short* __restrict__ W)
{
  __shared__ unsigned short als[16][512];
  const int tid = threadIdx.x;
  const int ng0 = blockIdx.x * 8;
  const int c0 = blockIdx.y * 512;
  const float *wsrc, *bsrc, *asrc;
  int nl0;
  if (ng0 < 4096)      { wsrc = wq; bsrc = bq; asrc = aq; nl0 = ng0; }
  else if (ng0 < 5120) { wsrc = wk; bsrc = bk; asrc = ak; nl0 = ng0 - 4096; }
  else                 { wsrc = wv; bsrc = bv; asrc = av; nl0 = ng0 - 5120; }
#pragma unroll
  for (int it = 0; it < 8; ++it) {
    int flat = it * 1024 + tid * 4;
    int r = flat >> 9, c = flat & 511;
    f32x4 v = *(const f32x4*)&asrc[(size_t)r * 4096 + c0 + c];
    short4v o;
#pragma unroll
    for (int e = 0; e < 4; ++e) o[e] = (short)f2bf(LORA_SCALE * v[e]);
    *(short4v*)&als[r][c] = o;
  }
  __syncthreads();
  const int nr = tid >> 5;
  const int cb = (tid & 31) * 16;
  const float* wrow = wsrc + (size_t)(nl0 + nr) * 4096 + c0 + cb;
  const float* brow = bsrc + (size_t)(nl0 + nr) * 16;
  float bb[16];
#pragma unroll
  for (int r4 = 0; r4 < 4; ++r4) {
    f32x4 t = *(const f32x4*)&brow[r4 * 4];
#pragma unroll
    for (int e = 0; e < 4; ++e) bb[r4 * 4 + e] = t[e];
  }
  float acc[16];
#pragma unroll
  for (int j4 = 0; j4 < 4; ++j4) {
    f32x4 t = *(const f32x4*)&wrow[j4 * 4];
#pragma unroll
    for (int e = 0; e < 4; ++e) acc[j4 * 4 + e] = t[e];
  }
#pragma unroll
  for (int r = 0; r < 16; ++r) {
    short8 a0 = *(const short8*)&als[r][cb];
    short8 a1 = *(const short8*)&als[r][cb + 8];
    float br = bb[r];
#pragma unroll
    for (int e = 0; e < 8; ++e) {
      acc[e]     += br * bf2f((unsigned short)a0[e]);
      acc[8 + e] += br * bf2f((unsigned short)a1[e]);
    }
  }
  short8 o0, o1;
#pragma unroll
  for (int e = 0; e < 8; ++e) { o0[e] = (short)f2bf(acc[e]); o1[e] = (short)f2bf(acc[8 + e]); }
  unsigned short* dst = W + (size_t)(ng0 + nr) * 4096 + c0 + cb;
  *(short8*)&dst[0] = o0;
  *(short8*)&dst[8] = o1;
}

__global__ void build_wo_kernel(const float* __restrict__ wo, const float* __restrict__ bo,
                                unsigned short* __restrict__ W)
{
  int idx = blockIdx.x * 256 + threadIdx.x;
  int n = idx / 520;
  int c8 = (idx - n * 520) * 8;
  short8 o;
  if (c8 < 4096) {
    const float* src = wo + (size_t)n * 4096 + c8;
    f32x4 a = *(const f32x4*)&src[0];
    f32x4 b2 = *(const f32x4*)&src[4];
#pragma unroll
    for (int e = 0; e < 4; ++e) { o[e] = (short)f2bf(a[e]); o[4 + e] = (short)f2bf(b2[e]); }
  } else {
#pragma unroll
    for (int e = 0; e < 8; ++e) {
      int j = c8 + e - 4096;
      float v = (j < 16) ? bo[(size_t)n * 16 + j] : 0.f;
      o[e] = (short)f2bf(v);
    }
  }
  *(short8*)&W[(size_t)n * 4160 + c8] = o;
}

__global__ __launch_bounds__(256) void convert_t_kernel(
    const float* __restrict__ x, const float* __restrict__ ao,
    unsigned short* __restrict__ Xb, unsigned short* __restrict__ Ao)
{
  __shared__ float red[4][16];
  const int m = blockIdx.x;
  const int tid = threadIdx.x;
  const int w = tid >> 6, l = tid & 63;
  float part[16];
#pragma unroll
  for (int r = 0; r < 16; ++r) part[r] = 0.f;
#pragma unroll
  for (int it = 0; it < 4; ++it) {
    int k = it * 1024 + tid * 4;
    f32x4 xv = *(const f32x4*)&x[(size_t)m * 4096 + k];
    short4v o;
#pragma unroll
    for (int e = 0; e < 4; ++e) o[e] = (short)f2bf(xv[e]);
    *(short4v*)&Xb[(size_t)m * 4096 + k] = o;
#pragma unroll
    for (int r = 0; r < 16; ++r) {
      f32x4 av = *(const f32x4*)&ao[(size_t)r * 4096 + k];
      part[r] += xv[0] * av[0] + xv[1] * av[1] + xv[2] * av[2] + xv[3] * av[3];
    }
  }
#pragma unroll
  for (int d = 1; d < 64; d <<= 1)
#pragma unroll
    for (int r = 0; r < 16; ++r) part[r] += __shfl_xor(part[r], d);
  if (l == 0)
#pragma unroll
    for (int r = 0; r < 16; ++r) red[w][r] = part[r];
  __syncthreads();
  if (tid < 64) {
    float v = 0.f;
    if (tid < 16) v = LORA_SCALE * (red[0][tid] + red[1][tid] + red[2][tid] + red[3][tid]);
    Ao[(size_t)m * 4160 + 4096 + tid] = f2bf(v);
  }
}

__global__ void rope_kernel(unsigned short* __restrict__ qkv,
                            const float* __restrict__ fcos,
                            const float* __restrict__ fsin)
{
  int idx = blockIdx.x * 256 + threadIdx.x;
  int m = idx / 640;
  int c8 = (idx - m * 640) * 8;
  int s = m & 2047;
  int i0 = (c8 & 127) >> 1;
  unsigned short* p = qkv + (size_t)m * 6144 + c8;
  short8 v = *(short8*)p;
  f32x4 c = *(const f32x4*)&fcos[s * 64 + i0];
  f32x4 sn = *(const f32x4*)&fsin[s * 64 + i0];
  short8 o;
#pragma unroll
  for (int pr = 0; pr < 4; ++pr) {
    float re = bf2f((unsigned short)v[2 * pr]);
    float im = bf2f((unsigned short)v[2 * pr + 1]);
    o[2 * pr]     = (short)f2bf(re * c[pr] - im * sn[pr]);
    o[2 * pr + 1] = (short)f2bf(re * sn[pr] + im * c[pr]);
  }
  *(short8*)p = o;
}

// ---------------------------------------------------------------- launch
extern "C" void kernel_launch(void* const* d_in, const int* in_sizes, int n_in,
                              void* d_out, int out_size, void* d_ws, size_t ws_size,
                              hipStream_t stream) {
  (void)in_sizes; (void)n_in; (void)out_size; (void)ws_size;
  const float* x    = (const float*)d_in[0];
  const float* w_q  = (const float*)d_in[1];
  const float* w_k  = (const float*)d_in[2];
  const float* w_v  = (const float*)d_in[3];
  const float* w_o  = (const float*)d_in[4];
  const float* la_q = (const float*)d_in[5];
  const float* lb_q = (const float*)d_in[6];
  const float* la_k = (const float*)d_in[7];
  const float* lb_k = (const float*)d_in[8];
  const float* la_v = (const float*)d_in[9];
  const float* lb_v = (const float*)d_in[10];
  const float* la_o = (const float*)d_in[11];
  const float* lb_o = (const float*)d_in[12];
  const float* fcos = (const float*)d_in[15];
  const float* fsin = (const float*)d_in[16];

  unsigned short* Wqkv = (unsigned short*)d_ws;              // 6144*4096
  unsigned short* Wo   = Wqkv + (size_t)6144 * 4096;         // 4096*4160
  unsigned short* Xbf  = Wo + (size_t)4096 * 4160;           // 4096*4096
  unsigned short* QKV  = Xbf + (size_t)4096 * 4096;          // 4096*6144
  unsigned short* Ao   = QKV + (size_t)4096 * 6144;          // 4096*4160

  dim3 blk(256);
  fold_all_kernel<<<dim3(768, 8), blk, 0, stream>>>(
      w_q, w_k, w_v, lb_q, lb_k, lb_v, la_q, la_k, la_v, Wqkv);
  build_wo_kernel<<<8320, blk, 0, stream>>>(w_o, lb_o, Wo);
  convert_t_kernel<<<4096, blk, 0, stream>>>(x, la_o, Xbf, Ao);
  gemm256c_kernel<1><<<dim3(24, 16), dim3(512), 0, stream>>>(Xbf, Wqkv, QKV, 4096, 6144, 128);
  rope_kernel<<<10240, blk, 0, stream>>>(QKV, fcos, fsin);
  flash_kernel<<<dim3(8, 32, 2), dim3(512), 0, stream>>>(QKV, Ao);
  gemm256_kernel<0><<<dim3(16, 16), dim3(512), 0, stream>>>(Ao, Wo, d_out, 4160, 4096, 65);
}

// Round 22
// 629.932 us; speedup vs baseline: 1.1351x; 1.0788x over previous
//
#include <hip/hip_runtime.h>

// Round 22 — FINAL: consolidation on the r19 optimum (630.5us validated).
// r20 (BK=32 2-phase) and r21 (BK=32 counted-vmcnt) both refuted the
// packing-over-schedule hypothesis; the BK=64 8-phase interleave wins.
// Components: gemm256 8-phase counted-vmcnt (2 barriers/K-tile, T1 swizzle),
// flash wave-split-paired with K via global_load_lds DMA, consolidated aux.
// q/k/v LoRA folded into weights; O-LoRA via augmented-K (applies to x).

typedef __attribute__((ext_vector_type(8))) short short8;
typedef __attribute__((ext_vector_type(4))) short short4v;
typedef __attribute__((ext_vector_type(4))) float f32x4;

#define LORA_SCALE 2.0f
#define INV_SQRT_HD 0.08838834764831845f

static __device__ __forceinline__ unsigned short f2bf(float f) {
  union { float f; unsigned int u; } v; v.f = f;
  unsigned int r = (v.u + 0x7fffu + ((v.u >> 16) & 1u)) >> 16;
  return (unsigned short)r;
}
static __device__ __forceinline__ float bf2f(unsigned short h) {
  union { unsigned int u; float f; } v; v.u = ((unsigned int)h) << 16;
  return v.f;
}

#define GL16(src, dst) __builtin_amdgcn_global_load_lds( \
    (const unsigned int __attribute__((address_space(1)))*)(src), \
    (unsigned int __attribute__((address_space(3)))*)(dst), 16, 0, 0)

#define VMC4() asm volatile("s_waitcnt vmcnt(4)" ::: "memory")
#define VMC0() asm volatile("s_waitcnt vmcnt(0)" ::: "memory")
#define BARX() __builtin_amdgcn_s_barrier()

// ---------------------------------------------------------------- GEMM 256x256 (8-phase, 2 barriers/K-tile, T1 swizzle)
template <int BF16OUT>
__global__ __launch_bounds__(512, 2) void gemm256_kernel(
    const unsigned short* __restrict__ A,
    const unsigned short* __restrict__ B,
    void* __restrict__ C, int K, int ldc, int T)
{
  __shared__ unsigned short As[2][2][8192];
  __shared__ unsigned short Bs[2][2][8192];
  const int tid = threadIdx.x;
  const int w = tid >> 6, l = tid & 63;
  const int l15 = l & 15, lhi = l >> 4;
  const int gx = gridDim.x;
  const int flat = blockIdx.y * gx + blockIdx.x;
  const int chunk = (gx * gridDim.y) >> 3;
  const int swz = (flat & 7) * chunk + (flat >> 3);
  const int m0 = (swz / gx) * 256, n0 = (swz % gx) * 256;
  const int wm = (w >> 2) * 128, wn = (w & 3) * 64;

  const f32x4 vz = {0.f, 0.f, 0.f, 0.f};
  f32x4 acc[8][4];
#pragma unroll
  for (int i = 0; i < 8; ++i)
#pragma unroll
    for (int j = 0; j < 4; ++j) acc[i][j] = vz;

  const int srow = tid >> 2, sg = tid & 3;
  const int sgsw = sg ^ ((tid >> 3) & 3);
  const unsigned short* gA = A + (size_t)(m0 + srow) * K + sgsw * 8;
  const unsigned short* gB = B + (size_t)(n0 + srow) * K + sgsw * 8;
  const size_t rK = (size_t)128 * K;
  const int ld0 = srow * 32 + sg * 8;

#define STAGE_A(buf, kh, kb) do { \
    GL16(gA + (kb) + (kh) * 32, &As[buf][kh][ld0]); \
    GL16(gA + rK + (kb) + (kh) * 32, &As[buf][kh][4096 + ld0]); } while (0)
#define STAGE_B(buf, kh, kb) do { \
    GL16(gB + (kb) + (kh) * 32, &Bs[buf][kh][ld0]); \
    GL16(gB + rK + (kb) + (kh) * 32, &Bs[buf][kh][4096 + ld0]); } while (0)
#define LDA8(buf, kc) do { \
    _Pragma("unroll") for (int mi = 0; mi < 8; ++mi) { \
      int r = wm + mi * 16 + l15; \
      af[mi] = *(const short8*)&As[buf][kc][r * 32 + ((lhi ^ ((r >> 1) & 3)) << 3)]; } } while (0)
#define LDB1(buf, kc, ni) \
    (*(const short8*)&Bs[buf][kc][(wn + (ni) * 16 + l15) * 32 + \
        ((lhi ^ (((wn + (ni) * 16 + l15) >> 1) & 3)) << 3)])
#define MM16(bx, by, cx, cy) do { \
    __builtin_amdgcn_s_setprio(1); \
    _Pragma("unroll") for (int mi = 0; mi < 8; ++mi) { \
      acc[mi][cx] = __builtin_amdgcn_mfma_f32_16x16x32_bf16(af[mi], bx, acc[mi][cx], 0, 0, 0); \
      acc[mi][cy] = __builtin_amdgcn_mfma_f32_16x16x32_bf16(af[mi], by, acc[mi][cy], 0, 0, 0); } \
    __builtin_amdgcn_s_setprio(0); } while (0)

  STAGE_A(0, 0, 0); STAGE_B(0, 0, 0); STAGE_A(0, 1, 0); STAGE_B(0, 1, 0);
  VMC4(); BARX();

  short8 af[8], b0, b1, b2, b3;
  for (int t = 0; t < T - 1; ++t) {
    const int cur = t & 1, nxt = cur ^ 1;
    const int kb = (t + 1) * 64;
    LDA8(cur, 0);
    b0 = LDB1(cur, 0, 0); b1 = LDB1(cur, 0, 1);
    STAGE_A(nxt, 0, kb);
    MM16(b0, b1, 0, 1);
    b2 = LDB1(cur, 0, 2); b3 = LDB1(cur, 0, 3);
    STAGE_B(nxt, 0, kb);
    VMC4(); BARX();
    MM16(b2, b3, 2, 3);
    LDA8(cur, 1);
    b0 = LDB1(cur, 1, 0); b1 = LDB1(cur, 1, 1);
    STAGE_A(nxt, 1, kb);
    MM16(b0, b1, 0, 1);
    b2 = LDB1(cur, 1, 2); b3 = LDB1(cur, 1, 3);
    STAGE_B(nxt, 1, kb);
    VMC4(); BARX();
    MM16(b2, b3, 2, 3);
  }
  {
    const int cur = (T - 1) & 1;
    LDA8(cur, 0);
    b0 = LDB1(cur, 0, 0); b1 = LDB1(cur, 0, 1);
    MM16(b0, b1, 0, 1);
    b2 = LDB1(cur, 0, 2); b3 = LDB1(cur, 0, 3);
    VMC0(); BARX();
    MM16(b2, b3, 2, 3);
    LDA8(cur, 1);
    b0 = LDB1(cur, 1, 0); b1 = LDB1(cur, 1, 1);
    MM16(b0, b1, 0, 1);
    b2 = LDB1(cur, 1, 2); b3 = LDB1(cur, 1, 3);
    MM16(b2, b3, 2, 3);
  }
#pragma unroll
  for (int mi = 0; mi < 8; ++mi)
#pragma unroll
    for (int ni = 0; ni < 4; ++ni)
#pragma unroll
      for (int j = 0; j < 4; ++j) {
        size_t row = (size_t)(m0 + wm + mi * 16 + lhi * 4 + j);
        size_t col = (size_t)(n0 + wn + ni * 16 + l15);
        if (BF16OUT) ((unsigned short*)C)[row * ldc + col] = f2bf(acc[mi][ni][j]);
        else         ((float*)C)[row * ldc + col] = acc[mi][ni][j];
      }
#undef STAGE_A
#undef STAGE_B
#undef LDA8
#undef LDB1
#undef MM16
}

// ---------------------------------------------------------------- flash per-tile body
__device__ __forceinline__ void flash_tile(
    const unsigned short* __restrict__ Ks,
    const unsigned short* __restrict__ Vt,
    unsigned short* __restrict__ Psw,
    const short8 (&qf)[2][4], f32x4 (&po)[2][8],
    float (&mrun)[2][4], float (&lrun)[2][4],
    int kv0, int qw0, int l15, int lhi)
{
  const f32x4 vzero = {0.f, 0.f, 0.f, 0.f};
  f32x4 sa[2][4];
#pragma unroll
  for (int mf = 0; mf < 2; ++mf)
#pragma unroll
    for (int nf = 0; nf < 4; ++nf) sa[mf][nf] = vzero;
  __builtin_amdgcn_s_setprio(1);
#pragma unroll
  for (int kc = 0; kc < 4; ++kc) {
    short8 kf[4];
#pragma unroll
    for (int nf = 0; nf < 4; ++nf) {
      int row = nf * 16 + l15;
      kf[nf] = *(const short8*)&Ks[row * 128 + ((kc * 32 + lhi * 8) ^ ((row & 7) << 3))];
    }
#pragma unroll
    for (int mf = 0; mf < 2; ++mf)
#pragma unroll
      for (int nf = 0; nf < 4; ++nf)
        sa[mf][nf] = __builtin_amdgcn_mfma_f32_16x16x32_bf16(qf[mf][kc], kf[nf], sa[mf][nf], 0, 0, 0);
  }
  __builtin_amdgcn_s_setprio(0);
  const bool diag = (kv0 + 63) > qw0;
#pragma unroll
  for (int mf = 0; mf < 2; ++mf) {
#pragma unroll
    for (int nf = 0; nf < 4; ++nf)
#pragma unroll
      for (int j = 0; j < 4; ++j) {
        float v = sa[mf][nf][j] * INV_SQRT_HD;
        if (diag) {
          int kvc = kv0 + nf * 16 + l15;
          int qr  = qw0 + mf * 16 + lhi * 4 + j;
          if (kvc > qr) v = -1e30f;
        }
        sa[mf][nf][j] = v;
      }
#pragma unroll
    for (int j = 0; j < 4; ++j) {
      float rm = fmaxf(fmaxf(sa[mf][0][j], sa[mf][1][j]), fmaxf(sa[mf][2][j], sa[mf][3][j]));
#pragma unroll
      for (int d = 1; d < 16; d <<= 1) rm = fmaxf(rm, __shfl_xor(rm, d));
      float mnew = fmaxf(mrun[mf][j], rm);
      float sc = __expf(mrun[mf][j] - mnew);
      float rs = 0.f;
#pragma unroll
      for (int nf = 0; nf < 4; ++nf) {
        float p = __expf(sa[mf][nf][j] - mnew);
        sa[mf][nf][j] = p;
        rs += p;
      }
#pragma unroll
      for (int d = 1; d < 16; d <<= 1) rs += __shfl_xor(rs, d);
      lrun[mf][j] = lrun[mf][j] * sc + rs;
      mrun[mf][j] = mnew;
#pragma unroll
      for (int df = 0; df < 8; ++df) po[mf][df][j] *= sc;
    }
#pragma unroll
    for (int j = 0; j < 4; ++j) {
      int q = mf * 16 + lhi * 4 + j;
      int sq = (q & 7) << 3;
#pragma unroll
      for (int nf = 0; nf < 4; ++nf)
        Psw[q * 64 + ((nf * 16 + l15) ^ sq)] = f2bf(sa[mf][nf][j]);
    }
  }
  __builtin_amdgcn_s_setprio(1);
#pragma unroll
  for (int kc2 = 0; kc2 < 2; ++kc2) {
    short8 pf[2];
#pragma unroll
    for (int mf = 0; mf < 2; ++mf) {
      int q = mf * 16 + l15;
      pf[mf] = *(const short8*)&Psw[q * 64 + ((kc2 * 32 + lhi * 8) ^ ((q & 7) << 3))];
    }
#pragma unroll
    for (int df = 0; df < 8; ++df) {
      int d = df * 16 + l15;
      int sv = ((d & 7) ^ ((d >> 3) & 7)) << 3;
      short8 vf = *(const short8*)&Vt[d * 64 + ((kc2 * 32 + lhi * 8) ^ sv)];
#pragma unroll
      for (int mf = 0; mf < 2; ++mf)
        po[mf][df] = __builtin_amdgcn_mfma_f32_16x16x32_bf16(pf[mf], vf, po[mf][df], 0, 0, 0);
    }
  }
  __builtin_amdgcn_s_setprio(0);
}

// ---------------------------------------------------------------- flash attention (wave-split pairing + K via DMA)
__global__ __launch_bounds__(512, 2) void flash_kernel(
    const unsigned short* __restrict__ qkv,
    unsigned short* __restrict__ outA)
{
  __shared__ unsigned short Ks[64 * 128];
  __shared__ unsigned short Vt[128 * 64];
  __shared__ unsigned short Ps[8][32 * 64];
  const int tid = threadIdx.x;
  const int w = tid >> 6, l = tid & 63;
  const int l15 = l & 15, lhi = l >> 4;
  const int h = blockIdx.y, b = blockIdx.z;
  const int p = (b == 0) ? (int)blockIdx.x : 7 - (int)blockIdx.x;
  const int qt = 2 * p + (w >> 2);
  const int qw0 = qt * 128 + (w & 3) * 32;
  const int kh = h >> 2;
  const size_t rowb = (size_t)b * 2048;

  short8 qf[2][4];
#pragma unroll
  for (int mf = 0; mf < 2; ++mf)
#pragma unroll
    for (int kc = 0; kc < 4; ++kc)
      qf[mf][kc] = *(const short8*)&qkv[(rowb + qw0 + mf * 16 + l15) * 6144 + h * 128 + kc * 32 + lhi * 8];

  const f32x4 vzero = {0.f, 0.f, 0.f, 0.f};
  f32x4 po[2][8];
  float mrun[2][4], lrun[2][4];
#pragma unroll
  for (int mf = 0; mf < 2; ++mf) {
#pragma unroll
    for (int df = 0; df < 8; ++df) po[mf][df] = vzero;
#pragma unroll
    for (int j = 0; j < 4; ++j) { mrun[mf][j] = -1e30f; lrun[mf][j] = 0.f; }
  }

  const int vrg = tid >> 4;
  const int vg  = tid & 15;

  const int nt = 2 * (2 * p + 1) + 2;
  for (int t = 0; t < nt; ++t) {
    const int kv0 = t * 64;
#pragma unroll
    for (int it = 0; it < 2; ++it) {
      int idx = it * 512 + tid;
      int r = idx >> 4, g = idx & 15;
      GL16(&qkv[(rowb + kv0 + r) * 6144 + 4096 + kh * 128 + ((g * 8) ^ ((r & 7) << 3))],
           &Ks[r * 128 + g * 8]);
    }
    if (tid < 256) {
      short8 v0, v1, v2, v3;
      const size_t vb = (rowb + kv0 + vrg * 4) * 6144 + kh * 128 + vg * 8 + 5120;
      v0 = *(const short8*)&qkv[vb];
      v1 = *(const short8*)&qkv[vb + 6144];
      v2 = *(const short8*)&qkv[vb + 12288];
      v3 = *(const short8*)&qkv[vb + 18432];
#pragma unroll
      for (int e = 0; e < 8; ++e) {
        int d = vg * 8 + e;
        int sv = ((d & 7) ^ ((d >> 3) & 7)) << 3;
        short4v o; o[0] = v0[e]; o[1] = v1[e]; o[2] = v2[e]; o[3] = v3[e];
        *(short4v*)&Vt[d * 64 + ((vrg * 4) ^ sv)] = o;
      }
    }
    __syncthreads();
    if (kv0 <= qw0 + 31)
      flash_tile(Ks, Vt, Ps[w], qf, po, mrun, lrun, kv0, qw0, l15, lhi);
    __syncthreads();
  }
#pragma unroll
  for (int mf = 0; mf < 2; ++mf)
#pragma unroll
    for (int df = 0; df < 8; ++df)
#pragma unroll
      for (int j = 0; j < 4; ++j) {
        size_t q = (size_t)(qw0 + mf * 16 + lhi * 4 + j);
        int d = df * 16 + l15;
        outA[(rowb + q) * 4160 + h * 128 + d] = f2bf(po[mf][df][j] / lrun[mf][j]);
      }
}

// ---------------------------------------------------------------- aux kernels (consolidated)
__global__ __launch_bounds__(256) void fold_all_kernel(
    const float* __restrict__ wq, const float* __restrict__ wk, const float* __restrict__ wv,
    const float* __restrict__ bq, const float* __restrict__ bk, const float* __restrict__ bv,
    const float* __restrict__ aq, const float* __restrict__ ak, const float* __restrict__ av,
    unsigned short* __restrict__ W)
{
  __shared__ unsigned short als[16][512];
  const int tid = threadIdx.x;
  const int ng0 = blockIdx.x * 8;
  const int c0 = blockIdx.y * 512;
  const float *wsrc, *bsrc, *asrc;
  int nl0;
  if (ng0 < 4096)      { wsrc = wq; bsrc = bq; asrc = aq; nl0 = ng0; }
  else if (ng0 < 5120) { wsrc = wk; bsrc = bk; asrc = ak; nl0 = ng0 - 4096; }
  else                 { wsrc = wv; bsrc = bv; asrc = av; nl0 = ng0 - 5120; }
#pragma unroll
  for (int it = 0; it < 8; ++it) {
    int flat = it * 1024 + tid * 4;
    int r = flat >> 9, c = flat & 511;
    f32x4 v = *(const f32x4*)&asrc[(size_t)r * 4096 + c0 + c];
    short4v o;
#pragma unroll
    for (int e = 0; e < 4; ++e) o[e] = (short)f2bf(LORA_SCALE * v[e]);
    *(short4v*)&als[r][c] = o;
  }
  __syncthreads();
  const int nr = tid >> 5;
  const int cb = (tid & 31) * 16;
  const float* wrow = wsrc + (size_t)(nl0 + nr) * 4096 + c0 + cb;
  const float* brow = bsrc + (size_t)(nl0 + nr) * 16;
  float bb[16];
#pragma unroll
  for (int r4 = 0; r4 < 4; ++r4) {
    f32x4 t = *(const f32x4*)&brow[r4 * 4];
#pragma unroll
    for (int e = 0; e < 4; ++e) bb[r4 * 4 + e] = t[e];
  }
  float acc[16];
#pragma unroll
  for (int j4 = 0; j4 < 4; ++j4) {
    f32x4 t = *(const f32x4*)&wrow[j4 * 4];
#pragma unroll
    for (int e = 0; e < 4; ++e) acc[j4 * 4 + e] = t[e];
  }
#pragma unroll
  for (int r = 0; r < 16; ++r) {
    short8 a0 = *(const short8*)&als[r][cb];
    short8 a1 = *(const short8*)&als[r][cb + 8];
    float br = bb[r];
#pragma unroll
    for (int e = 0; e < 8; ++e) {
      acc[e]     += br * bf2f((unsigned short)a0[e]);
      acc[8 + e] += br * bf2f((unsigned short)a1[e]);
    }
  }
  short8 o0, o1;
#pragma unroll
  for (int e = 0; e < 8; ++e) { o0[e] = (short)f2bf(acc[e]); o1[e] = (short)f2bf(acc[8 + e]); }
  unsigned short* dst = W + (size_t)(ng0 + nr) * 4096 + c0 + cb;
  *(short8*)&dst[0] = o0;
  *(short8*)&dst[8] = o1;
}

__global__ void build_wo_kernel(const float* __restrict__ wo, const float* __restrict__ bo,
                                unsigned short* __restrict__ W)
{
  int idx = blockIdx.x * 256 + threadIdx.x;
  int n = idx / 520;
  int c8 = (idx - n * 520) * 8;
  short8 o;
  if (c8 < 4096) {
    const float* src = wo + (size_t)n * 4096 + c8;
    f32x4 a = *(const f32x4*)&src[0];
    f32x4 b2 = *(const f32x4*)&src[4];
#pragma unroll
    for (int e = 0; e < 4; ++e) { o[e] = (short)f2bf(a[e]); o[4 + e] = (short)f2bf(b2[e]); }
  } else {
#pragma unroll
    for (int e = 0; e < 8; ++e) {
      int j = c8 + e - 4096;
      float v = (j < 16) ? bo[(size_t)n * 16 + j] : 0.f;
      o[e] = (short)f2bf(v);
    }
  }
  *(short8*)&W[(size_t)n * 4160 + c8] = o;
}

__global__ __launch_bounds__(256) void convert_t_kernel(
    const float* __restrict__ x, const float* __restrict__ ao,
    unsigned short* __restrict__ Xb, unsigned short* __restrict__ Ao)
{
  __shared__ float red[4][16];
  const int m = blockIdx.x;
  const int tid = threadIdx.x;
  const int w = tid >> 6, l = tid & 63;
  float part[16];
#pragma unroll
  for (int r = 0; r < 16; ++r) part[r] = 0.f;
#pragma unroll
  for (int it = 0; it < 4; ++it) {
    int k = it * 1024 + tid * 4;
    f32x4 xv = *(const f32x4*)&x[(size_t)m * 4096 + k];
    short4v o;
#pragma unroll
    for (int e = 0; e < 4; ++e) o[e] = (short)f2bf(xv[e]);
    *(short4v*)&Xb[(size_t)m * 4096 + k] = o;
#pragma unroll
    for (int r = 0; r < 16; ++r) {
      f32x4 av = *(const f32x4*)&ao[(size_t)r * 4096 + k];
      part[r] += xv[0] * av[0] + xv[1] * av[1] + xv[2] * av[2] + xv[3] * av[3];
    }
  }
#pragma unroll
  for (int d = 1; d < 64; d <<= 1)
#pragma unroll
    for (int r = 0; r < 16; ++r) part[r] += __shfl_xor(part[r], d);
  if (l == 0)
#pragma unroll
    for (int r = 0; r < 16; ++r) red[w][r] = part[r];
  __syncthreads();
  if (tid < 64) {
    float v = 0.f;
    if (tid < 16) v = LORA_SCALE * (red[0][tid] + red[1][tid] + red[2][tid] + red[3][tid]);
    Ao[(size_t)m * 4160 + 4096 + tid] = f2bf(v);
  }
}

__global__ void rope_kernel(unsigned short* __restrict__ qkv,
                            const float* __restrict__ fcos,
                            const float* __restrict__ fsin)
{
  int idx = blockIdx.x * 256 + threadIdx.x;
  int m = idx / 640;
  int c8 = (idx - m * 640) * 8;
  int s = m & 2047;
  int i0 = (c8 & 127) >> 1;
  unsigned short* p = qkv + (size_t)m * 6144 + c8;
  short8 v = *(short8*)p;
  f32x4 c = *(const f32x4*)&fcos[s * 64 + i0];
  f32x4 sn = *(const f32x4*)&fsin[s * 64 + i0];
  short8 o;
#pragma unroll
  for (int pr = 0; pr < 4; ++pr) {
    float re = bf2f((unsigned short)v[2 * pr]);
    float im = bf2f((unsigned short)v[2 * pr + 1]);
    o[2 * pr]     = (short)f2bf(re * c[pr] - im * sn[pr]);
    o[2 * pr + 1] = (short)f2bf(re * sn[pr] + im * c[pr]);
  }
  *(short8*)p = o;
}

// ---------------------------------------------------------------- launch
extern "C" void kernel_launch(void* const* d_in, const int* in_sizes, int n_in,
                              void* d_out, int out_size, void* d_ws, size_t ws_size,
                              hipStream_t stream) {
  (void)in_sizes; (void)n_in; (void)out_size; (void)ws_size;
  const float* x    = (const float*)d_in[0];
  const float* w_q  = (const float*)d_in[1];
  const float* w_k  = (const float*)d_in[2];
  const float* w_v  = (const float*)d_in[3];
  const float* w_o  = (const float*)d_in[4];
  const float* la_q = (const float*)d_in[5];
  const float* lb_q = (const float*)d_in[6];
  const float* la_k = (const float*)d_in[7];
  const float* lb_k = (const float*)d_in[8];
  const float* la_v = (const float*)d_in[9];
  const float* lb_v = (const float*)d_in[10];
  const float* la_o = (const float*)d_in[11];
  const float* lb_o = (const float*)d_in[12];
  const float* fcos = (const float*)d_in[15];
  const float* fsin = (const float*)d_in[16];

  unsigned short* Wqkv = (unsigned short*)d_ws;              // 6144*4096
  unsigned short* Wo   = Wqkv + (size_t)6144 * 4096;         // 4096*4160
  unsigned short* Xbf  = Wo + (size_t)4096 * 4160;           // 4096*4096
  unsigned short* QKV  = Xbf + (size_t)4096 * 4096;          // 4096*6144
  unsigned short* Ao   = QKV + (size_t)4096 * 6144;          // 4096*4160

  dim3 blk(256);
  fold_all_kernel<<<dim3(768, 8), blk, 0, stream>>>(
      w_q, w_k, w_v, lb_q, lb_k, lb_v, la_q, la_k, la_v, Wqkv);
  build_wo_kernel<<<8320, blk, 0, stream>>>(w_o, lb_o, Wo);
  convert_t_kernel<<<4096, blk, 0, stream>>>(x, la_o, Xbf, Ao);
  gemm256_kernel<1><<<dim3(24, 16), dim3(512), 0, stream>>>(Xbf, Wqkv, QKV, 4096, 6144, 64);
  rope_kernel<<<10240, blk, 0, stream>>>(QKV, fcos, fsin);
  flash_kernel<<<dim3(8, 32, 2), dim3(512), 0, stream>>>(QKV, Ao);
  gemm256_kernel<0><<<dim3(16, 16), dim3(512), 0, stream>>>(Ao, Wo, d_out, 4160, 4096, 65);
}